// Round 2
// baseline (3163.974 us; speedup 1.0000x reference)
//
#include <hip/hip_runtime.h>
#include <cstdint>
#include <cstddef>

constexpr int N_NODES = 65536;
constexpr int D       = 128;
constexpr int E_EDGES = 524288;
constexpr int LVLS    = 8;
constexpr int EL      = E_EDGES / LVLS;   // 65536

__device__ __forceinline__ float sigmoidf_(float x) { return 1.0f / (1.0f + expf(-x)); }

__device__ __forceinline__ float wave_sum(float v) {
#pragma unroll
    for (int off = 32; off > 0; off >>= 1) v += __shfl_down(v, off, 64);
    return v;
}

// ---------------------------------------------------------------------------
// K0: u_dir[c] = sum_d We[d][c] * wa2[d];  cst = be.wa2 + ba
__global__ __launch_bounds__(256)
void prep_kernel(const float* __restrict__ We_f, const float* __restrict__ Wa_f,
                 const float* __restrict__ be_f, const float* __restrict__ ba_f,
                 const float* __restrict__ We_b, const float* __restrict__ Wa_b,
                 const float* __restrict__ be_b, const float* __restrict__ ba_b,
                 float* __restrict__ u_f, float* __restrict__ u_b, float* __restrict__ cst)
{
    int t = threadIdx.x;
    if (t < 128) {
        float s = 0.f;
        for (int d = 0; d < 128; ++d) s = fmaf(We_f[d * 128 + t], Wa_f[128 + d], s);
        u_f[t] = s;
    } else {
        int c = t - 128;
        float s = 0.f;
        for (int d = 0; d < 128; ++d) s = fmaf(We_b[d * 128 + c], Wa_b[128 + d], s);
        u_b[c] = s;
    }
    if (t == 0) {
        float s = 0.f;
        for (int d = 0; d < 128; ++d) s = fmaf(be_f[d], Wa_f[128 + d], s);
        cst[0] = s + ba_f[0];
    }
    if (t == 255) {
        float s = 0.f;
        for (int d = 0; d < 128; ++d) s = fmaf(be_b[d], Wa_b[128 + d], s);
        cst[1] = s + ba_b[0];
    }
}

// ---------------------------------------------------------------------------
// K1: edot for both directions in one pass over edge_attr (wave per edge)
__global__ __launch_bounds__(256)
void edot_kernel(const float* __restrict__ ea, const float* __restrict__ u_f,
                 const float* __restrict__ u_b, const float* __restrict__ cst,
                 float* __restrict__ edot_f, float* __restrict__ edot_b)
{
    int wv = threadIdx.x >> 6, lane = threadIdx.x & 63;
    int e = blockIdx.x * 4 + wv;
    if (e >= E_EDGES) return;
    int d = lane << 1;
    float2 v  = *reinterpret_cast<const float2*>(ea + (size_t)e * 128 + d);
    float2 uf = *reinterpret_cast<const float2*>(u_f + d);
    float2 ub = *reinterpret_cast<const float2*>(u_b + d);
    float af = v.x * uf.x + v.y * uf.y;
    float ab = v.x * ub.x + v.y * ub.y;
    af = wave_sum(af);
    ab = wave_sum(ab);
    if (lane == 0) {
        edot_f[e] = af + cst[0];
        edot_b[e] = ab + cst[1];
    }
}

// ---------------------------------------------------------------------------
// K2: mark nodes that ever appear as aggregation target (per direction)
__global__ __launch_bounds__(256)
void set_flags_kernel(const int* __restrict__ ei, int* __restrict__ flag_f,
                      int* __restrict__ flag_b)
{
    int e = blockIdx.x * 256 + threadIdx.x;
    if (e >= E_EDGES) return;
    flag_b[ei[e]] = 1;            // src: backward targets
    flag_f[ei[E_EDGES + e]] = 1;  // dst: forward targets
}

// ---------------------------------------------------------------------------
// Generic C = A @ W^T + bias   (A: [M,128], W: [384,128], C: [M,384])
// Optional row gather: rows/counter != nullptr -> M = *counter, A-row = rows[r]
#define BM 64
#define BN 64
#define BK 32
__global__ __launch_bounds__(256, 2)
void gemm_bias(const float* __restrict__ A, const float* __restrict__ W,
               const float* __restrict__ bias, float* __restrict__ C,
               int M_fixed, const int* __restrict__ counter, const int* __restrict__ rows)
{
    int M = rows ? *counter : M_fixed;
    int row0 = blockIdx.x * BM;
    if (row0 >= M) return;
    int col0 = blockIdx.y * BN;

    __shared__ __align__(16) float Ast[BK][BM + 4];  // transposed A tile
    __shared__ __align__(16) float Bs[BK][BN + 4];

    int tid = threadIdx.x;
    int ty = tid >> 4, tx = tid & 15;

    float acc[4][4] = {};

    int lr = tid >> 3;           // 0..31 (A rows per pass)
    int lc = (tid & 7) << 2;     // k-col within tile (float4)
    int bn = tid >> 2;           // 0..63 (W row within tile)
    int bk = (tid & 3) << 3;     // k-col (2x float4)

    for (int k0 = 0; k0 < 128; k0 += BK) {
#pragma unroll
        for (int rr = 0; rr < 2; ++rr) {
            int r = lr + rr * 32;
            int grow = row0 + r;
            float4 v = make_float4(0.f, 0.f, 0.f, 0.f);
            if (grow < M) {
                int arow = rows ? rows[grow] : grow;
                v = *reinterpret_cast<const float4*>(A + (size_t)arow * 128 + k0 + lc);
            }
            Ast[lc + 0][r] = v.x; Ast[lc + 1][r] = v.y;
            Ast[lc + 2][r] = v.z; Ast[lc + 3][r] = v.w;
        }
        const float* wrow = W + (size_t)(col0 + bn) * 128 + k0 + bk;
#pragma unroll
        for (int q = 0; q < 2; ++q) {
            float4 v = *reinterpret_cast<const float4*>(wrow + q * 4);
            Bs[bk + q * 4 + 0][bn] = v.x; Bs[bk + q * 4 + 1][bn] = v.y;
            Bs[bk + q * 4 + 2][bn] = v.z; Bs[bk + q * 4 + 3][bn] = v.w;
        }
        __syncthreads();
#pragma unroll
        for (int k = 0; k < BK; ++k) {
            float4 a = *reinterpret_cast<const float4*>(&Ast[k][ty << 2]);
            float4 b = *reinterpret_cast<const float4*>(&Bs[k][tx << 2]);
            float av[4] = {a.x, a.y, a.z, a.w};
            float bv[4] = {b.x, b.y, b.z, b.w};
#pragma unroll
            for (int i2 = 0; i2 < 4; ++i2)
#pragma unroll
                for (int j2 = 0; j2 < 4; ++j2)
                    acc[i2][j2] = fmaf(av[i2], bv[j2], acc[i2][j2]);
        }
        __syncthreads();
    }
#pragma unroll
    for (int i2 = 0; i2 < 4; ++i2) {
        int r = row0 + (ty << 2) + i2;
        if (r < M) {
            const float* bp = bias + col0 + (tx << 2);
            float4 o;
            o.x = acc[i2][0] + bp[0];
            o.y = acc[i2][1] + bp[1];
            o.z = acc[i2][2] + bp[2];
            o.w = acc[i2][3] + bp[3];
            *reinterpret_cast<float4*>(C + (size_t)r * 384 + col0 + (tx << 2)) = o;
        }
    }
}

// ---------------------------------------------------------------------------
// K4: root init: h = root ? (1-z)*n : 0 ; also qdot = h_prev.wa1, hdot = h.wa2
__global__ __launch_bounds__(256)
void init_h_kernel(const float* __restrict__ gi, const float* __restrict__ hp,
                   const float* __restrict__ bh, const int* __restrict__ flag,
                   const float* __restrict__ wa, float* __restrict__ h,
                   float* __restrict__ qdot, float* __restrict__ hdot)
{
    int wv = threadIdx.x >> 6, lane = threadIdx.x & 63;
    int n = blockIdx.x * 4 + wv;
    if (n >= N_NODES) return;
    bool root = (flag[n] == 0);
    const float* gir = gi + (size_t)n * 384;
    int d = lane << 1;
    float2 hpv = *reinterpret_cast<const float2*>(hp + (size_t)n * 128 + d);
    float hv[2] = {0.f, 0.f};
    if (root) {
#pragma unroll
        for (int q = 0; q < 2; ++q) {
            int dd = d + q;
            float r  = sigmoidf_(gir[dd] + bh[dd]);
            float z  = sigmoidf_(gir[128 + dd] + bh[128 + dd]);
            float nn = tanhf(gir[256 + dd] + r * bh[256 + dd]);
            hv[q] = (1.f - z) * nn;   // z*hidden with hidden==0
        }
    }
    *reinterpret_cast<float2*>(h + (size_t)n * 128 + d) = make_float2(hv[0], hv[1]);
    float hd = hv[0] * wa[128 + d] + hv[1] * wa[128 + d + 1];
    float qd = hpv.x * wa[d] + hpv.y * wa[d + 1];
    hd = wave_sum(hd);
    qd = wave_sum(qd);
    if (lane == 0) { hdot[n] = hd; qdot[n] = qd; }
}

// ---------------------------------------------------------------------------
// K6: per edge: alpha = qdot[i]+hdot[j]+edot[ge]; ex=exp(alpha); den[i]+=ex
__global__ __launch_bounds__(256)
void edge_pass1(const int* __restrict__ jidx, const int* __restrict__ iidx,
                const float* __restrict__ edot, const float* __restrict__ qdot,
                const float* __restrict__ hdot, float* __restrict__ ex,
                float* __restrict__ den, int base)
{
    int e = blockIdx.x * 256 + threadIdx.x;
    if (e >= EL) return;
    int ge = base + e;
    int j = jidx[ge], i = iidx[ge];
    float alpha = qdot[i] + hdot[j] + edot[ge];
    float x = expf(alpha);
    ex[e] = x;
    atomicAdd(&den[i], x);
}

// ---------------------------------------------------------------------------
// K7: wave per edge: msg[i] += (ex/den[i]) * h[j]
__global__ __launch_bounds__(256)
void edge_pass2(const int* __restrict__ jidx, const int* __restrict__ iidx,
                const float* __restrict__ ex, const float* __restrict__ den,
                const float* __restrict__ h, float* __restrict__ msg, int base)
{
    int wv = threadIdx.x >> 6, lane = threadIdx.x & 63;
    int e = blockIdx.x * 4 + wv;
    if (e >= EL) return;
    int ge = base + e;
    int j = jidx[ge], i = iidx[ge];
    float a = ex[e] / den[i];
    int d = lane << 1;
    float2 v = *reinterpret_cast<const float2*>(h + (size_t)j * 128 + d);
    atomicAdd(msg + (size_t)i * 128 + d, a * v.x);
    atomicAdd(msg + (size_t)i * 128 + d + 1, a * v.y);
}

// ---------------------------------------------------------------------------
// K8: compact masked nodes (den>0) into rows[]
__global__ __launch_bounds__(256)
void compact_kernel(const float* __restrict__ den, int* __restrict__ rows,
                    int* __restrict__ counter)
{
    int n = blockIdx.x * 256 + threadIdx.x;
    if (n >= N_NODES) return;
    if (den[n] > 0.f) {
        int p = atomicAdd(counter, 1);
        rows[p] = n;
    }
}

// ---------------------------------------------------------------------------
// K9b: GRU elementwise for masked nodes; h_new = (1-z)*n + z*msg (hidden=msg!)
__global__ __launch_bounds__(256)
void gru_update_kernel(const float* __restrict__ gi, const float* __restrict__ gh,
                       const float* __restrict__ msg, const int* __restrict__ rows,
                       const int* __restrict__ counter, const float* __restrict__ wa,
                       float* __restrict__ h, float* __restrict__ hdot)
{
    int wv = threadIdx.x >> 6, lane = threadIdx.x & 63;
    int gr = blockIdx.x * 4 + wv;
    if (gr >= *counter) return;
    int n = rows[gr];
    const float* gir = gi + (size_t)n * 384;
    const float* ghr = gh + (size_t)gr * 384;
    int d = lane << 1;
    float2 msgv = *reinterpret_cast<const float2*>(msg + (size_t)n * 128 + d);
    float hv[2];
#pragma unroll
    for (int q = 0; q < 2; ++q) {
        int dd = d + q;
        float r  = sigmoidf_(gir[dd] + ghr[dd]);
        float z  = sigmoidf_(gir[128 + dd] + ghr[128 + dd]);
        float nn = tanhf(gir[256 + dd] + r * ghr[256 + dd]);
        float hid = (q == 0) ? msgv.x : msgv.y;   // hidden = msg, NOT h_prev
        hv[q] = (1.f - z) * nn + z * hid;
    }
    *reinterpret_cast<float2*>(h + (size_t)n * 128 + d) = make_float2(hv[0], hv[1]);
    float hd = hv[0] * wa[128 + d] + hv[1] * wa[128 + d + 1];
    hd = wave_sum(hd);
    if (lane == 0) hdot[n] = hd;
}

// ---------------------------------------------------------------------------
__global__ __launch_bounds__(256)
void relu_kernel(const float* __restrict__ h, float* __restrict__ out)
{
    int idx = (blockIdx.x * 256 + threadIdx.x) * 4;
    float4 v = *reinterpret_cast<const float4*>(h + idx);
    v.x = fmaxf(v.x, 0.f); v.y = fmaxf(v.y, 0.f);
    v.z = fmaxf(v.z, 0.f); v.w = fmaxf(v.w, 0.f);
    *reinterpret_cast<float4*>(out + idx) = v;
}

// ---------------------------------------------------------------------------
extern "C" void kernel_launch(void* const* d_in, const int* in_sizes, int n_in,
                              void* d_out, int out_size, void* d_ws, size_t ws_size,
                              hipStream_t stream)
{
    (void)in_sizes; (void)n_in; (void)out_size; (void)ws_size;

    const float* x    = (const float*)d_in[0];
    const int*   ei   = (const int*)d_in[1];
    const float* ea   = (const float*)d_in[2];
    const float* We_f = (const float*)d_in[4];
    const float* be_f = (const float*)d_in[5];
    const float* Wa_f = (const float*)d_in[6];
    const float* ba_f = (const float*)d_in[7];
    const float* Wi_f = (const float*)d_in[8];
    const float* Wh_f = (const float*)d_in[9];
    const float* bi_f = (const float*)d_in[10];
    const float* bh_f = (const float*)d_in[11];
    const float* We_b = (const float*)d_in[12];
    const float* be_b = (const float*)d_in[13];
    const float* Wa_b = (const float*)d_in[14];
    const float* ba_b = (const float*)d_in[15];
    const float* Wi_b = (const float*)d_in[16];
    const float* Wh_b = (const float*)d_in[17];
    const float* bi_b = (const float*)d_in[18];
    const float* bh_b = (const float*)d_in[19];
    float* out = (float*)d_out;

    char* p = (char*)d_ws;
    auto carve = [&](size_t bytes) -> char* {
        char* r = p;
        p += (bytes + 255) & ~(size_t)255;
        return r;
    };
    float* u_f    = (float*)carve((size_t)D * 4);
    float* u_b    = (float*)carve((size_t)D * 4);
    float* cst    = (float*)carve(16);
    float* edot_f = (float*)carve((size_t)E_EDGES * 4);
    float* edot_b = (float*)carve((size_t)E_EDGES * 4);
    int*   flag_f = (int*)carve((size_t)N_NODES * 4);
    int*   flag_b = (int*)carve((size_t)N_NODES * 4);
    float* gi     = (float*)carve((size_t)N_NODES * 384 * 4);
    float* gh     = (float*)carve((size_t)N_NODES * 384 * 4);
    float* h_fwd  = (float*)carve((size_t)N_NODES * D * 4);
    float* h_cur  = (float*)carve((size_t)N_NODES * D * 4);
    float* msg    = (float*)carve((size_t)N_NODES * D * 4);
    float* qdot   = (float*)carve((size_t)N_NODES * 4);
    float* hdot   = (float*)carve((size_t)N_NODES * 4);
    float* den    = (float*)carve((size_t)N_NODES * 4);
    float* ex     = (float*)carve((size_t)EL * 4);
    int*   rows   = (int*)carve((size_t)N_NODES * 4);
    int*   counter= (int*)carve(256);

    prep_kernel<<<1, 256, 0, stream>>>(We_f, Wa_f, be_f, ba_f, We_b, Wa_b, be_b, ba_b,
                                       u_f, u_b, cst);
    hipMemsetAsync(flag_f, 0, (size_t)N_NODES * 4, stream);
    hipMemsetAsync(flag_b, 0, (size_t)N_NODES * 4, stream);
    set_flags_kernel<<<E_EDGES / 256, 256, 0, stream>>>(ei, flag_f, flag_b);
    edot_kernel<<<E_EDGES / 4, 256, 0, stream>>>(ea, u_f, u_b, cst, edot_f, edot_b);

    for (int dir = 0; dir < 2; ++dir) {
        const float* hp   = dir == 0 ? x : h_fwd;
        float*       h    = dir == 0 ? h_fwd : h_cur;
        const float* Wi   = dir == 0 ? Wi_f : Wi_b;
        const float* bi   = dir == 0 ? bi_f : bi_b;
        const float* Wh   = dir == 0 ? Wh_f : Wh_b;
        const float* bh   = dir == 0 ? bh_f : bh_b;
        const float* wa   = dir == 0 ? Wa_f : Wa_b;
        const int*   flag = dir == 0 ? flag_f : flag_b;
        const float* edot = dir == 0 ? edot_f : edot_b;
        const int*   jidx = dir == 0 ? ei : ei + E_EDGES;          // message source
        const int*   iidx = dir == 0 ? ei + E_EDGES : ei;          // aggregation target

        gemm_bias<<<dim3(N_NODES / BM, 384 / BN), 256, 0, stream>>>(
            hp, Wi, bi, gi, N_NODES, nullptr, nullptr);
        init_h_kernel<<<N_NODES / 4, 256, 0, stream>>>(gi, hp, bh, flag, wa, h, qdot, hdot);

        for (int t = 0; t < LVLS; ++t) {
            int lv = dir == 0 ? t : (LVLS - 1 - t);
            int base = lv * EL;
            hipMemsetAsync(msg, 0, (size_t)N_NODES * D * 4, stream);
            hipMemsetAsync(den, 0, (size_t)N_NODES * 4, stream);
            hipMemsetAsync(counter, 0, 4, stream);
            edge_pass1<<<EL / 256, 256, 0, stream>>>(jidx, iidx, edot, qdot, hdot, ex, den, base);
            edge_pass2<<<EL / 4, 256, 0, stream>>>(jidx, iidx, ex, den, h, msg, base);
            compact_kernel<<<N_NODES / 256, 256, 0, stream>>>(den, rows, counter);
            gemm_bias<<<dim3(N_NODES / BM, 384 / BN), 256, 0, stream>>>(
                msg, Wh, bh, gh, 0, counter, rows);
            gru_update_kernel<<<N_NODES / 4, 256, 0, stream>>>(gi, gh, msg, rows, counter,
                                                               wa, h, hdot);
        }
    }
    relu_kernel<<<(N_NODES * D) / 1024, 256, 0, stream>>>(h_cur, out);
}

// Round 7
// 2795.353 us; speedup vs baseline: 1.1319x; 1.1319x over previous
//
#include <hip/hip_runtime.h>
#include <cstdint>
#include <cstddef>

constexpr int N_NODES = 65536;
constexpr int D       = 128;
constexpr int E_EDGES = 524288;
constexpr int LVLS    = 8;
constexpr int EL      = E_EDGES / LVLS;   // 65536

typedef unsigned int  u32;
typedef unsigned short u16;
typedef __attribute__((ext_vector_type(8)))  short short8;   // 8 bf16 (4 VGPR)
typedef __attribute__((ext_vector_type(16))) float f32x16;

__device__ __forceinline__ float sigmoidf_(float x) { return 1.0f / (1.0f + expf(-x)); }

__device__ __forceinline__ u32 bf_hi(float f) {           // f32 -> bf16 bits (RNE)
    u32 x = __float_as_uint(f);
    return (x + 0x7fffu + ((x >> 16) & 1u)) >> 16;
}
__device__ __forceinline__ float bf_f(u32 hbits) { return __uint_as_float(hbits << 16); }

// Swizzled byte offset inside a [rows][32 bf16] LDS tile (64B rows).
// XOR only bits 4-5: permutes the four 16B slots WITHIN the 64B row ->
// bijective (the previous (row&7)<<4 escaped the row slot and collided
// across 8-row stripe boundaries). Column-slice b128 reads become 4-way
// bank conflicts instead of 16-way unswizzled.
__device__ __forceinline__ int swz(int row, int kbyte) {
    return row * 64 + (kbyte ^ ((row & 3) << 4));
}

__device__ __forceinline__ float wave_sum(float v) {
#pragma unroll
    for (int off = 32; off > 0; off >>= 1) v += __shfl_down(v, off, 64);
    return v;
}

// ---------------------------------------------------------------------------
// u_dir[c] = sum_d We[d][c]*wa2[d];  cst = be.wa2 + ba
__global__ __launch_bounds__(256)
void prep_kernel(const float* __restrict__ We_f, const float* __restrict__ Wa_f,
                 const float* __restrict__ be_f, const float* __restrict__ ba_f,
                 const float* __restrict__ We_b, const float* __restrict__ Wa_b,
                 const float* __restrict__ be_b, const float* __restrict__ ba_b,
                 float* __restrict__ u_f, float* __restrict__ u_b, float* __restrict__ cst)
{
    int t = threadIdx.x;
    if (t < 128) {
        float s = 0.f;
        for (int d = 0; d < 128; ++d) s = fmaf(We_f[d * 128 + t], Wa_f[128 + d], s);
        u_f[t] = s;
    } else {
        int c = t - 128;
        float s = 0.f;
        for (int d = 0; d < 128; ++d) s = fmaf(We_b[d * 128 + c], Wa_b[128 + d], s);
        u_b[c] = s;
    }
    if (t == 0) {
        float s = 0.f;
        for (int d = 0; d < 128; ++d) s = fmaf(be_f[d], Wa_f[128 + d], s);
        cst[0] = s + ba_f[0];
    }
    if (t == 255) {
        float s = 0.f;
        for (int d = 0; d < 128; ++d) s = fmaf(be_b[d], Wa_b[128 + d], s);
        cst[1] = s + ba_b[0];
    }
}

// ---------------------------------------------------------------------------
__global__ __launch_bounds__(256)
void convert_w(const float* __restrict__ W, u16* __restrict__ Whi, u16* __restrict__ Wlo)
{
    int i = blockIdx.x * 256 + threadIdx.x;   // grid covers 384*128 exactly
    float v = W[i];
    u32 hb = bf_hi(v);
    Whi[i] = (u16)hb;
    Wlo[i] = (u16)bf_hi(v - bf_f(hb));
}

// ---------------------------------------------------------------------------
__global__ __launch_bounds__(256)
void edot_kernel(const float* __restrict__ ea, const float* __restrict__ u_f,
                 const float* __restrict__ u_b, const float* __restrict__ cst,
                 float* __restrict__ edot_f, float* __restrict__ edot_b)
{
    int wv = threadIdx.x >> 6, lane = threadIdx.x & 63;
    int e = blockIdx.x * 4 + wv;
    if (e >= E_EDGES) return;
    int d = lane << 1;
    float2 v  = *reinterpret_cast<const float2*>(ea + (size_t)e * 128 + d);
    float2 uf = *reinterpret_cast<const float2*>(u_f + d);
    float2 ub = *reinterpret_cast<const float2*>(u_b + d);
    float af = wave_sum(v.x * uf.x + v.y * uf.y);
    float ab = wave_sum(v.x * ub.x + v.y * ub.y);
    if (lane == 0) {
        edot_f[e] = af + cst[0];
        edot_b[e] = ab + cst[1];
    }
}

// ---------------------------------------------------------------------------
__global__ __launch_bounds__(256)
void set_flags_kernel(const int* __restrict__ ei, int* __restrict__ flag_f,
                      int* __restrict__ flag_b)
{
    int e = blockIdx.x * 256 + threadIdx.x;
    if (e >= E_EDGES) return;
    flag_b[ei[e]] = 1;            // src: backward targets
    flag_f[ei[E_EDGES + e]] = 1;  // dst: forward targets
}

// ---------------------------------------------------------------------------
// Fused split-bf16 MFMA GEMM (C = A @ W^T, K=128, Ncols=384) + GRU epilogue.
// MODE 0: A=h_prev, W=Wi. Writes gi(+bi) for flagged nodes, h-init for roots,
//         qdot, hdot. M = 65536 (no gather).
// MODE 1: A=msg (gathered via rows[0..cnt)), W=Wh. Full GRU using gi (global),
//         writes h, hdot; self-clears msg/den/seen for consumed rows.
// Block: 128 rows x 384 cols, 512 thr = 8 waves: wave w -> q=w&3 (col slices
// q*32 +{0,128,256}), mh=w>>2 (row half). Per wave: 2 m-tiles x 3 gates of
// 32x32 acc. Split-bf16: acc += Ah*Wh + Ah*Wl + Al*Wh.
template<int MODE>
__global__ __launch_bounds__(512, 2)
void gemm_fused(const float* __restrict__ A,
                const u16* __restrict__ Whi, const u16* __restrict__ Wlo,
                const int* __restrict__ pcnt, const int* __restrict__ rows,
                const float* __restrict__ bi,
                const float* __restrict__ bh,
                const float* __restrict__ wa,
                const int* __restrict__ flag,
                float* __restrict__ gi,
                float* __restrict__ h,
                float* __restrict__ hdot, float* __restrict__ qdot,
                float* __restrict__ msg_c, float* __restrict__ den,
                int* __restrict__ seen)
{
    __shared__ __align__(16) unsigned char smem[16384 + 49152 + 4096 + 512];
    unsigned char* As = smem;               // [2 halves][128][32 bf16] swizzled
    unsigned char* Bs = smem + 16384;       // [2 halves][384][32 bf16] swizzled
    float* red   = (float*)(smem + 16384 + 49152);      // [128][4] (+[128][4] qdot)
    int* rowsLds = (int*)(smem + 16384 + 49152 + 4096); // [128]

    const int tid = threadIdx.x;
    int cnt;
    if constexpr (MODE == 0) cnt = N_NODES; else cnt = *pcnt;
    const int row0 = blockIdx.x * 128;
    if (row0 >= cnt) return;

    if constexpr (MODE == 1) {
        if (tid < 128) rowsLds[tid] = rows[row0 + tid];
    }
    __syncthreads();

    f32x16 acc[2][3];
#pragma unroll
    for (int mt = 0; mt < 2; ++mt)
#pragma unroll
        for (int g = 0; g < 3; ++g) acc[mt][g] = (f32x16)0.0f;

    const int lane = tid & 63, wv = tid >> 6;
    const int q = wv & 3, mh = wv >> 2;
    const int l31 = lane & 31, l5 = lane >> 5;

    for (int k0 = 0; k0 < 128; k0 += 32) {
        // ---- stage A (f32 -> bf16 hi/lo): 128 rows x 32 k
#pragma unroll
        for (int p = 0; p < 2; ++p) {
            int idx = tid + p * 512;
            int rw = idx >> 3, kf = (idx & 7) << 2;
            float4 v = make_float4(0.f, 0.f, 0.f, 0.f);
            if constexpr (MODE == 0) {
                v = *reinterpret_cast<const float4*>(A + (size_t)(row0 + rw) * 128 + k0 + kf);
            } else {
                if (row0 + rw < cnt)
                    v = *reinterpret_cast<const float4*>(A + (size_t)rowsLds[rw] * 128 + k0 + kf);
            }
            u32 h0 = bf_hi(v.x), h1 = bf_hi(v.y), h2 = bf_hi(v.z), h3 = bf_hi(v.w);
            u32 l0 = bf_hi(v.x - bf_f(h0)), l1 = bf_hi(v.y - bf_f(h1));
            u32 l2 = bf_hi(v.z - bf_f(h2)), l3 = bf_hi(v.w - bf_f(h3));
            int off = swz(rw, kf * 2);
            *reinterpret_cast<uint2*>(As + off)        = make_uint2(h0 | (h1 << 16), h2 | (h3 << 16));
            *reinterpret_cast<uint2*>(As + 8192 + off) = make_uint2(l0 | (l1 << 16), l2 | (l3 << 16));
        }
        // ---- stage B (preconverted bf16 hi/lo): 384 rows x 32 k x 2 halves
#pragma unroll
        for (int p = 0; p < 6; ++p) {
            int c = tid + p * 512;
            int hf = c & 1, cc = c >> 1;
            int rw = cc >> 2, kc = cc & 3;
            const u16* src = hf ? Wlo : Whi;
            uint4 v = *reinterpret_cast<const uint4*>(src + (size_t)rw * 128 + k0 + kc * 8);
            *reinterpret_cast<uint4*>(Bs + hf * 24576 + swz(rw, kc * 16)) = v;
        }
        __syncthreads();
        // ---- MFMA
#pragma unroll
        for (int kh = 0; kh < 2; ++kh) {
            short8 a[2][2], b[3][2];
#pragma unroll
            for (int mt = 0; mt < 2; ++mt)
#pragma unroll
                for (int hf = 0; hf < 2; ++hf)
                    a[mt][hf] = *reinterpret_cast<const short8*>(
                        As + hf * 8192 + swz(mh * 64 + mt * 32 + l31, kh * 32 + l5 * 16));
#pragma unroll
            for (int g = 0; g < 3; ++g)
#pragma unroll
                for (int hf = 0; hf < 2; ++hf)
                    b[g][hf] = *reinterpret_cast<const short8*>(
                        Bs + hf * 24576 + swz(q * 32 + g * 128 + l31, kh * 32 + l5 * 16));
#pragma unroll
            for (int mt = 0; mt < 2; ++mt)
#pragma unroll
                for (int g = 0; g < 3; ++g) {
                    acc[mt][g] = __builtin_amdgcn_mfma_f32_32x32x16_bf16(a[mt][0], b[g][0], acc[mt][g], 0, 0, 0);
                    acc[mt][g] = __builtin_amdgcn_mfma_f32_32x32x16_bf16(a[mt][0], b[g][1], acc[mt][g], 0, 0, 0);
                    acc[mt][g] = __builtin_amdgcn_mfma_f32_32x32x16_bf16(a[mt][1], b[g][0], acc[mt][g], 0, 0, 0);
                }
        }
        __syncthreads();
    }

    // ---- epilogue
    const int d = q * 32 + l31;
    const float wa2d = wa[128 + d];
    const float bh0 = bh[d], bh1 = bh[d + 128], bh2 = bh[d + 256];
    float bi0 = 0.f, bi1 = 0.f, bi2 = 0.f, wa1d = 0.f;
    if constexpr (MODE == 0) {
        bi0 = bi[d]; bi1 = bi[d + 128]; bi2 = bi[d + 256]; wa1d = wa[d];
    }

#pragma unroll
    for (int mt = 0; mt < 2; ++mt)
#pragma unroll
        for (int rg = 0; rg < 16; ++rg) {
            int rl = mh * 64 + mt * 32 + (rg & 3) + ((rg >> 2) << 3) + (l5 << 2);
            int gr = row0 + rl;
            float hv = 0.f, pq = 0.f;
            if constexpr (MODE == 0) {
                int n = gr;
                int fl = flag[n];
                float g0 = acc[mt][0][rg] + bi0;
                float g1 = acc[mt][1][rg] + bi1;
                float g2 = acc[mt][2][rg] + bi2;
                if (fl) {
                    gi[(size_t)n * 384 + d]       = g0;
                    gi[(size_t)n * 384 + d + 128] = g1;
                    gi[(size_t)n * 384 + d + 256] = g2;
                } else {
                    float rr = sigmoidf_(g0 + bh0);
                    float zz = sigmoidf_(g1 + bh1);
                    float nn = tanhf(g2 + rr * bh2);
                    hv = (1.f - zz) * nn;          // hidden = 0 for roots
                }
                h[(size_t)n * 128 + d] = hv;
                pq = A[(size_t)n * 128 + d] * wa1d;  // A == h_prev
            } else {
                bool ok = gr < cnt;
                int n = ok ? rowsLds[rl] : 0;
                const float* gin = gi + (size_t)n * 384;
                float mval = msg_c[(size_t)n * 128 + d];
                float rr = sigmoidf_(gin[d]       + acc[mt][0][rg] + bh0);
                float zz = sigmoidf_(gin[d + 128] + acc[mt][1][rg] + bh1);
                float nn = tanhf(gin[d + 256] + rr * (acc[mt][2][rg] + bh2));
                hv = (1.f - zz) * nn + zz * mval;    // hidden = msg
                if (ok) h[(size_t)n * 128 + d] = hv;
            }
            float pd = hv * wa2d;
#pragma unroll
            for (int o = 1; o < 32; o <<= 1) pd += __shfl_xor(pd, o, 64);
            if constexpr (MODE == 0) {
#pragma unroll
                for (int o = 1; o < 32; o <<= 1) pq += __shfl_xor(pq, o, 64);
            }
            if (l31 == 0) {
                red[rl * 4 + q] = pd;
                if constexpr (MODE == 0) red[512 + rl * 4 + q] = pq;
            }
        }
    __syncthreads();
    if (tid < 128) {
        int gr = row0 + tid;
        if (gr < cnt) {
            int n;
            if constexpr (MODE == 0) n = gr; else n = rowsLds[tid];
            hdot[n] = red[tid * 4] + red[tid * 4 + 1] + red[tid * 4 + 2] + red[tid * 4 + 3];
            if constexpr (MODE == 0)
                qdot[n] = red[512 + tid * 4] + red[512 + tid * 4 + 1] +
                          red[512 + tid * 4 + 2] + red[512 + tid * 4 + 3];
            if constexpr (MODE == 1) { den[n] = 0.f; seen[n] = 0; }
        }
    }
    if constexpr (MODE == 1) {
#pragma unroll
        for (int p = 0; p < 8; ++p) {
            int idx = tid + p * 512;
            int rl = idx >> 5, c4 = (idx & 31) << 2;
            if (row0 + rl < cnt)
                *reinterpret_cast<float4*>(msg_c + (size_t)rowsLds[rl] * 128 + c4) =
                    make_float4(0.f, 0.f, 0.f, 0.f);
        }
    }
}

// ---------------------------------------------------------------------------
// alpha = qdot[i]+hdot[j]+edot; ex=exp(alpha); den[i]+=ex; claim rows list.
__global__ __launch_bounds__(256)
void edge_pass1(const int* __restrict__ jidx, const int* __restrict__ iidx,
                const float* __restrict__ edot, const float* __restrict__ qdot,
                const float* __restrict__ hdot, float* __restrict__ ex,
                float* __restrict__ den, int* __restrict__ seen,
                int* __restrict__ rows, int* __restrict__ counter, int base)
{
    int e = blockIdx.x * 256 + threadIdx.x;
    int ge = base + e;
    int j = jidx[ge], i = iidx[ge];
    float x = expf(qdot[i] + hdot[j] + edot[ge]);
    ex[e] = x;
    atomicAdd(&den[i], x);
    if (atomicExch(&seen[i], 1) == 0) {
        int p = atomicAdd(counter, 1);
        rows[p] = i;
    }
}

// ---------------------------------------------------------------------------
// wave per edge: msg[i] += (ex/den[i]) * h[j]
__global__ __launch_bounds__(256)
void edge_pass2(const int* __restrict__ jidx, const int* __restrict__ iidx,
                const float* __restrict__ ex, const float* __restrict__ den,
                const float* __restrict__ h, float* __restrict__ msg, int base)
{
    int wv = threadIdx.x >> 6, lane = threadIdx.x & 63;
    int e = blockIdx.x * 4 + wv;
    if (e >= EL) return;
    int ge = base + e;
    int j = jidx[ge], i = iidx[ge];
    float a = ex[e] / den[i];
    int d = lane << 1;
    float2 v = *reinterpret_cast<const float2*>(h + (size_t)j * 128 + d);
    atomicAdd(msg + (size_t)i * 128 + d, a * v.x);
    atomicAdd(msg + (size_t)i * 128 + d + 1, a * v.y);
}

// ---------------------------------------------------------------------------
__global__ __launch_bounds__(256)
void relu_kernel(const float* __restrict__ h, float* __restrict__ out)
{
    int idx = (blockIdx.x * 256 + threadIdx.x) * 4;
    float4 v = *reinterpret_cast<const float4*>(h + idx);
    v.x = fmaxf(v.x, 0.f); v.y = fmaxf(v.y, 0.f);
    v.z = fmaxf(v.z, 0.f); v.w = fmaxf(v.w, 0.f);
    *reinterpret_cast<float4*>(out + idx) = v;
}

// ---------------------------------------------------------------------------
extern "C" void kernel_launch(void* const* d_in, const int* in_sizes, int n_in,
                              void* d_out, int out_size, void* d_ws, size_t ws_size,
                              hipStream_t stream)
{
    (void)in_sizes; (void)n_in; (void)out_size; (void)ws_size;

    const float* x    = (const float*)d_in[0];
    const int*   ei   = (const int*)d_in[1];
    const float* ea   = (const float*)d_in[2];
    const float* We_f = (const float*)d_in[4];
    const float* be_f = (const float*)d_in[5];
    const float* Wa_f = (const float*)d_in[6];
    const float* ba_f = (const float*)d_in[7];
    const float* Wi_f = (const float*)d_in[8];
    const float* Wh_f = (const float*)d_in[9];
    const float* bi_f = (const float*)d_in[10];
    const float* bh_f = (const float*)d_in[11];
    const float* We_b = (const float*)d_in[12];
    const float* be_b = (const float*)d_in[13];
    const float* Wa_b = (const float*)d_in[14];
    const float* ba_b = (const float*)d_in[15];
    const float* Wi_b = (const float*)d_in[16];
    const float* Wh_b = (const float*)d_in[17];
    const float* bi_b = (const float*)d_in[18];
    const float* bh_b = (const float*)d_in[19];
    float* out = (float*)d_out;

    char* p = (char*)d_ws;
    auto carve = [&](size_t bytes) -> char* {
        char* r = p;
        p += (bytes + 255) & ~(size_t)255;
        return r;
    };
    // ---- zeroed region (contiguous, one memset) ----
    float* msg     = (float*)carve((size_t)N_NODES * D * 4);   // 32 MB
    float* den     = (float*)carve((size_t)N_NODES * 4);
    int*   seen    = (int*)carve((size_t)N_NODES * 4);
    int*   flag_f  = (int*)carve((size_t)N_NODES * 4);
    int*   flag_b  = (int*)carve((size_t)N_NODES * 4);
    int*   counters= (int*)carve(256);                          // 16 used
    size_t zbytes  = (size_t)((char*)counters - (char*)msg) + 256;
    // ---- rest ----
    u16* WiF_hi = (u16*)carve(384 * 128 * 2); u16* WiF_lo = (u16*)carve(384 * 128 * 2);
    u16* WhF_hi = (u16*)carve(384 * 128 * 2); u16* WhF_lo = (u16*)carve(384 * 128 * 2);
    u16* WiB_hi = (u16*)carve(384 * 128 * 2); u16* WiB_lo = (u16*)carve(384 * 128 * 2);
    u16* WhB_hi = (u16*)carve(384 * 128 * 2); u16* WhB_lo = (u16*)carve(384 * 128 * 2);
    float* u_f    = (float*)carve((size_t)D * 4);
    float* u_b    = (float*)carve((size_t)D * 4);
    float* cst    = (float*)carve(16);
    float* edot_f = (float*)carve((size_t)E_EDGES * 4);
    float* edot_b = (float*)carve((size_t)E_EDGES * 4);
    float* gi     = (float*)carve((size_t)N_NODES * 384 * 4);  // 96 MB
    float* h_fwd  = (float*)carve((size_t)N_NODES * D * 4);
    float* h_cur  = (float*)carve((size_t)N_NODES * D * 4);
    float* qdot   = (float*)carve((size_t)N_NODES * 4);
    float* hdot   = (float*)carve((size_t)N_NODES * 4);
    float* ex     = (float*)carve((size_t)EL * 4);
    int*   rows   = (int*)carve((size_t)N_NODES * 4);

    hipMemsetAsync(msg, 0, zbytes, stream);
    prep_kernel<<<1, 256, 0, stream>>>(We_f, Wa_f, be_f, ba_f, We_b, Wa_b, be_b, ba_b,
                                       u_f, u_b, cst);
    convert_w<<<192, 256, 0, stream>>>(Wi_f, WiF_hi, WiF_lo);
    convert_w<<<192, 256, 0, stream>>>(Wh_f, WhF_hi, WhF_lo);
    convert_w<<<192, 256, 0, stream>>>(Wi_b, WiB_hi, WiB_lo);
    convert_w<<<192, 256, 0, stream>>>(Wh_b, WhB_hi, WhB_lo);
    set_flags_kernel<<<E_EDGES / 256, 256, 0, stream>>>(ei, flag_f, flag_b);
    edot_kernel<<<E_EDGES / 4, 256, 0, stream>>>(ea, u_f, u_b, cst, edot_f, edot_b);

    for (int dir = 0; dir < 2; ++dir) {
        const float* hp   = dir == 0 ? x : h_fwd;
        float*       h    = dir == 0 ? h_fwd : h_cur;
        const u16*   Wihi = dir == 0 ? WiF_hi : WiB_hi;
        const u16*   Wilo = dir == 0 ? WiF_lo : WiB_lo;
        const u16*   Whhi = dir == 0 ? WhF_hi : WhB_hi;
        const u16*   Whlo = dir == 0 ? WhF_lo : WhB_lo;
        const float* bi   = dir == 0 ? bi_f : bi_b;
        const float* bh   = dir == 0 ? bh_f : bh_b;
        const float* wa   = dir == 0 ? Wa_f : Wa_b;
        const int*   flag = dir == 0 ? flag_f : flag_b;
        const float* edot = dir == 0 ? edot_f : edot_b;
        const int*   jidx = dir == 0 ? ei : ei + E_EDGES;   // message source
        const int*   iidx = dir == 0 ? ei + E_EDGES : ei;   // aggregation target

        gemm_fused<0><<<512, 512, 0, stream>>>(
            hp, Wihi, Wilo, nullptr, nullptr, bi, bh, wa, flag,
            gi, h, hdot, qdot, nullptr, nullptr, nullptr);

        for (int t = 0; t < LVLS; ++t) {
            int lv = dir == 0 ? t : (LVLS - 1 - t);
            int base = lv * EL;
            int gt = dir * LVLS + t;
            edge_pass1<<<EL / 256, 256, 0, stream>>>(jidx, iidx, edot, qdot, hdot,
                                                     ex, den, seen, rows, counters + gt, base);
            edge_pass2<<<EL / 4, 256, 0, stream>>>(jidx, iidx, ex, den, h, msg, base);
            gemm_fused<1><<<512, 512, 0, stream>>>(
                msg, Whhi, Whlo, counters + gt, rows, nullptr, bh, wa, nullptr,
                gi, h, hdot, nullptr, msg, den, seen);
        }
    }
    relu_kernel<<<(N_NODES * D) / 1024, 256, 0, stream>>>(h_cur, out);
}